// Round 12
// baseline (1892.470 us; speedup 1.0000x reference)
//
#include <hip/hip_runtime.h>
#include <hip/hip_bf16.h>
#include <hip/hip_fp16.h>

#define B_ 64
#define L_ 128
#define C_ 256
#define DH_ 128
#define DF_ 50
#define R_ 4

typedef __attribute__((ext_vector_type(8))) short short8_;
typedef __attribute__((ext_vector_type(4))) float f32x4_;
typedef _Float16 half2_ __attribute__((ext_vector_type(2)));

__device__ __forceinline__ float sigmoidf_(float x){ return 1.0f/(1.0f+expf(-x)); }
// fast sigmoid: v_rcp approx (~1e-6 rel) instead of precise division; tolerance is 2e-3
__device__ __forceinline__ float fsig_(float x){
#if __has_builtin(__builtin_amdgcn_rcpf)
    return __builtin_amdgcn_rcpf(1.0f + __expf(-x));
#else
    return 1.0f/(1.0f+__expf(-x));
#endif
}

__device__ __forceinline__ unsigned short f2bf(float f){
    unsigned u = __builtin_bit_cast(unsigned, f);
    unsigned r = (u + 0x7FFFu + ((u >> 16) & 1u)) >> 16;
    return (unsigned short)r;
}
__device__ __forceinline__ unsigned short f2bf_hw(float f){
    return __builtin_bit_cast(unsigned short, __float2bfloat16(f));
}
__device__ __host__ __forceinline__ unsigned short f2h(float f){
    return __builtin_bit_cast(unsigned short, (_Float16)f);
}
// packed f16 dot: acc += a.lo*b.lo + a.hi*b.hi  (v_dot2_f32_f16 if available)
__device__ __forceinline__ float dot2_(unsigned a, unsigned b, float c){
#if __has_builtin(__builtin_amdgcn_fdot2)
    return __builtin_amdgcn_fdot2(__builtin_bit_cast(half2_, a),
                                  __builtin_bit_cast(half2_, b), c, false);
#else
    half2_ ah = __builtin_bit_cast(half2_, a), bh = __builtin_bit_cast(half2_, b);
    return c + (float)ah.x*(float)bh.x + (float)ah.y*(float)bh.y;
#endif
}

// bf16 h-state swizzle (8-col groups XORed by row&7)
#define HB(r,c) ((r)*128 + ((c) ^ (((r)&7)<<3)))

// ---------------- Precompute: column sums of gate3_W factor rows ----------------
__global__ void k_ssum(const float* __restrict__ g3W, float* __restrict__ ssum){
    int h = threadIdx.x;
    for (int s = 0; s < 3; s++){
        float a = 0.f;
        for (int j = 0; j < DF_; j++) a += g3W[(2*DH_ + s*DF_ + j)*DH_ + h];
        ssum[s*DH_ + h] = a;
    }
}

// ------- Precompute: acts -------------------------------------------------------
__global__ void k_acts4(const int* __restrict__ q_seq, const int* __restrict__ c_seq,
                        const float* __restrict__ embQ, const float* __restrict__ embC,
                        const float* __restrict__ inW, const float* __restrict__ inB,
                        float* __restrict__ acts){
    int bt0 = blockIdx.x*4; int h = threadIdx.x;
    __shared__ float qe[4][DH_], ce[4][DH_];
    #pragma unroll
    for (int s = 0; s < 4; s++){
        qe[s][h] = embQ[(size_t)q_seq[bt0+s]*DH_ + h];
        ce[s][h] = embC[(size_t)c_seq[bt0+s]*DH_ + h];
    }
    __syncthreads();
    float a0 = inB[h], a1 = a0, a2 = a0, a3 = a0;
    for (int i = 0; i < DH_; i++){
        float w = inW[i*DH_ + h];
        a0 += qe[0][i]*w; a1 += qe[1][i]*w; a2 += qe[2][i]*w; a3 += qe[3][i]*w;
    }
    for (int i = 0; i < DH_; i++){
        float w = inW[(DH_+i)*DH_ + h];
        a0 += ce[0][i]*w; a1 += ce[1][i]*w; a2 += ce[2][i]*w; a3 += ce[3][i]*w;
    }
    acts[(size_t)(bt0+0)*DH_+h] = fmaxf(a0,0.f);
    acts[(size_t)(bt0+1)*DH_+h] = fmaxf(a1,0.f);
    acts[(size_t)(bt0+2)*DH_+h] = fmaxf(a2,0.f);
    acts[(size_t)(bt0+3)*DH_+h] = fmaxf(a3,0.f);
}

// ------- Precompute: per-(b,t) bias bases + gates -------------------------------
__global__ void k_base4(const int* __restrict__ q_seq,
                        const float* __restrict__ tfs, const float* __restrict__ afs,
                        const float* __restrict__ hfs,
                        const float* __restrict__ acts, const float* __restrict__ embQ,
                        const float* __restrict__ tgW, const float* __restrict__ tgb,
                        const float* __restrict__ agW, const float* __restrict__ agb,
                        const float* __restrict__ hgW, const float* __restrict__ hgb,
                        const float* __restrict__ g3W, const float* __restrict__ g3b,
                        const float* __restrict__ outW, const float* __restrict__ outb,
                        const float* __restrict__ ssum,
                        float* __restrict__ actT, float* __restrict__ actA,
                        float* __restrict__ actH,
                        float* __restrict__ fbase, float* __restrict__ predt,
                        float* __restrict__ gateT, float* __restrict__ gateA,
                        float* __restrict__ gateH){
    int bt0 = blockIdx.x*4; int h = threadIdx.x;
    __shared__ float al[4][DH_], qe[4][DH_];
    #pragma unroll
    for (int s = 0; s < 4; s++){
        al[s][h] = acts[(size_t)(bt0+s)*DH_ + h];
        qe[s][h] = embQ[(size_t)q_seq[bt0+s]*DH_ + h];
    }
    __syncthreads();
    float aT[4]={0,0,0,0}, aA[4]={0,0,0,0}, aH[4]={0,0,0,0}, aF[4]={0,0,0,0}, aP[4]={0,0,0,0};
    for (int i = 0; i < DH_; i++){
        float wt = tgW[(DH_+i)*DH_+h];
        float wa = agW[(DH_+i)*DH_+h];
        float wh = hgW[(DH_+i)*DH_+h];
        float wf = g3W[(DH_+i)*DH_+h];
        float wo = outW[(DH_+i)*DH_+h];
        #pragma unroll
        for (int s = 0; s < 4; s++){
            float av = al[s][i], qv = qe[s][i];
            aT[s] += av*wt; aA[s] += av*wa; aH[s] += av*wh;
            aF[s] += av*wf; aP[s] += qv*wo;
        }
    }
    #pragma unroll
    for (int s = 0; s < 4; s++){
        int bt = bt0 + s;
        actT[(size_t)bt*DH_+h]  = aT[s] + tgb[h];
        actA[(size_t)bt*DH_+h]  = aA[s] + agb[h];
        actH[(size_t)bt*DH_+h]  = aH[s] + hgb[h];
        fbase[(size_t)bt*DH_+h] = aF[s] + g3b[h]
            + tfs[bt]*ssum[h] + afs[bt]*ssum[DH_+h] + hfs[bt]*ssum[2*DH_+h];
        predt[(size_t)bt*DH_+h] = aP[s] + outb[h];
    }
    if (h == 0){
        #pragma unroll
        for (int s = 0; s < 4; s++){
            int bt = bt0+s;
            gateT[bt] = 0.7f + 0.3f*sigmoidf_(10.f*(tfs[bt]-0.3f));
            gateA[bt] = 0.7f + 0.3f*sigmoidf_(10.f*(afs[bt]-0.3f));
            gateH[bt] = 0.7f + 0.3f*sigmoidf_(10.f*(hfs[bt]-0.3f));
        }
    }
}

// ------- Precompute: G weights, COALESCED layout, f16 --------------------------
// gwch[(i8*512 + gx*128 + gh)*8 + j] = f16( W_gx[(i8*8+j)*128 + gh] )
__global__ void k_wG(const float* __restrict__ tgW, const float* __restrict__ agW,
                     const float* __restrict__ hgW, const float* __restrict__ outW,
                     unsigned short* __restrict__ gwch){
    int flat = blockIdx.x*256 + threadIdx.x;     // < 65536
    int j = flat & 7, t512 = (flat >> 3) & 511, i8 = flat >> 12;
    int gx = t512 >> 7, gh = t512 & 127, i = i8*8 + j;
    const float* W = (gx==0)?tgW:((gx==1)?agW:((gx==2)?hgW:outW));
    gwch[flat] = f2h(W[i*DH_ + gh]);
}
// ------- Precompute: L weights, COALESCED blocked split-K, f16 -----------------
// thread tidv: hh=tidv>>3, rr=(tidv>>1)&3, kh=tidv&1
// dst[(ii*1024 + tidv)*8 + j] = f16( w[(rr*129 + kh*64 + ii*8 + j)*128 + hh] )
__global__ void k_wL(const float* __restrict__ tw, const float* __restrict__ aw,
                     const float* __restrict__ hw,
                     unsigned short* __restrict__ twch, unsigned short* __restrict__ awch,
                     unsigned short* __restrict__ hwch, float* __restrict__ lbias){
    int flat = blockIdx.x*256 + threadIdx.x;
    if (flat < 3*65536){
        int m = flat >> 16, fi = flat & 65535;
        int j = fi & 7, tidv = (fi >> 3) & 1023, ii = fi >> 13;
        int hh = tidv >> 3, rr = (tidv >> 1) & 3, kh = tidv & 1;
        int i = kh*64 + ii*8 + j;
        const float* w = (m==0)?tw:((m==1)?aw:hw);
        unsigned short* dst = (m==0)?twch:((m==1)?awch:hwch);
        dst[fi] = f2h(w[((size_t)(rr*129 + i))*DH_ + hh]);
    } else if (flat < 3*65536 + 3*4*128){
        int f2 = flat - 3*65536;
        int m = f2 >> 9, r = (f2 >> 7) & 3, h = f2 & 127;
        const float* w = (m==0)?tw:((m==1)?aw:hw);
        lbias[f2] = w[((size_t)(r*129 + 128))*DH_ + h];
    }
}

// ---------------- Recurrence: one block per b, 1024 threads, 16 waves ----------
// R9 skeleton (4 barriers) + breg B-fragment register cache + pred-out in P2.
// amdgpu_waves_per_eu(4,4): LDS caps us at 1 block/CU = 4 waves/SIMD anyway;
// pinning it raises the VGPR budget to 128 so breg[8] (32 VGPR) stays resident
// (launch_bounds' 2nd arg is only a MIN -> allocator targeted 8 waves = 64 VGPR
// and spilled every added array in R4/R10/R11).
//  P1: W0-7 G-dot full-K (f16 dot2); W8-15 stage t+1
//  P2: ALL waves L-dot split-K (f16 dot2) -> lgl; pred-out from pp
//  P3: MFMA forget (kk=0 from regs) + epilogue (fast-rcp sigmoid)
//  P4: reduce htl(t+1), store packed f16
__global__ __attribute__((amdgpu_flat_work_group_size(1024,1024), amdgpu_waves_per_eu(4,4)))
void k_one(const int* __restrict__ q_seq, const float* __restrict__ q_matrix,
           const float* __restrict__ init_h, const float* __restrict__ g3W,
           const unsigned short* __restrict__ gwch,
           const unsigned short* __restrict__ twch, const unsigned short* __restrict__ awch,
           const unsigned short* __restrict__ hwch,
           const float* __restrict__ lbias, const float* __restrict__ Wf,
           const float* __restrict__ cellb,
           const float* __restrict__ actT, const float* __restrict__ actA,
           const float* __restrict__ actH,
           const float* __restrict__ fbase, const float* __restrict__ predt,
           const float* __restrict__ gateT, const float* __restrict__ gateA,
           const float* __restrict__ gateH,
           float* __restrict__ out){
    int b = blockIdx.x;
    int tid = threadIdx.x;
    int l = tid & 63, wv = tid >> 6, kb = l >> 4, l15 = l & 15;

    __shared__ unsigned short hl[C_*DH_];        // 64 KB bf16 h state (wave-private rows)
    __shared__ unsigned short bflds[2048*8];     // 32 KB g3W B-fragments
    __shared__ float phtp[16][DH_];              // 8 KB
    __shared__ __align__(16) unsigned short htf[DH_];   // h_tilde packed f16
    __shared__ __align__(16) unsigned sgf[3*80]; // gates f16: x*80 + kh*40 + e(32)
    __shared__ float pp[DH_];
    __shared__ float lgl[DH_];
    __shared__ float stg[2][5][DH_];             // actT,actA,actH,predt,fbase
    __shared__ float gtl[2][4];
    __shared__ float cwb[2][C_];                 // corr_w double-buffer

    // L-dot ids (blocked split-K)
    int kh = tid & 1;
    int rr3 = (tid >> 1) & 3, hh = tid >> 3;
    float kmask = kh ? 0.f : 1.f;
    float lb0 = kmask*lbias[(0*4+rr3)*DH_ + hh];
    float lb1 = kmask*lbias[(1*4+rr3)*DH_ + hh];
    float lb2 = kmask*lbias[(2*4+rr3)*DH_ + hh];
    float wfr = Wf[rr3];
    float cbr = cellb[hh];

    // build B-fragments in LDS (2 per thread)
    #pragma unroll
    for (int ff = 0; ff < 2; ff++){
        int f = tid*2 + ff;
        int fl = f & 63, fn0 = (f >> 6) & 7, fkk = f >> 9;
        #pragma unroll
        for (int j = 0; j < 8; j++){
            int k = fkk*32 + (fl>>4)*8 + j;
            int n = fn0*16 + (fl&15);
            bflds[f*8 + j] = f2bf(g3W[k*DH_ + n]);
        }
    }

    // h-regs init: wave owns 16 rows (wv*16..+15), all cols
    float hreg[8][4];
    #pragma unroll
    for (int n0 = 0; n0 < 8; n0++)
    #pragma unroll
    for (int j = 0; j < 4; j++){
        int row = wv*16 + kb*4 + j;
        int hc = n0*16 + l15;
        float v = init_h[row*DH_ + hc];
        hreg[n0][j] = v;
        hl[HB(row, hc)] = f2bf(v);
    }
    // pre-loop staging of buffer 0 (t=0 data)
    {
        int bt0 = b*L_;
        int s = tid;
        if (s < 128)      stg[0][0][s]     = actT [(size_t)bt0*DH_ + s];
        else if (s < 256) stg[0][1][s-128] = actA [(size_t)bt0*DH_ + (s-128)];
        else if (s < 384) stg[0][2][s-256] = actH [(size_t)bt0*DH_ + (s-256)];
        else if (s < 512) stg[0][3][s-384] = predt[(size_t)bt0*DH_ + (s-384)];
        else if (s < 640) stg[0][4][s-512] = fbase[(size_t)bt0*DH_ + (s-512)];
        else if (s < 896){ int q0 = q_seq[bt0]; cwb[0][s-640] = q_matrix[(size_t)q0*C_ + (s-640)]; }
        else if (s == 896) gtl[0][0] = gateT[bt0];
        else if (s == 897) gtl[0][1] = gateA[bt0];
        else if (s == 898) gtl[0][2] = gateH[bt0];
    }
    __syncthreads();
    // kk=0 B-fragments resident in registers (8 x short8 = 32 VGPR), loaded ONCE
    short8_ breg[8];
    {
        const short8_* bp = (const short8_*)bflds;
        #pragma unroll
        for (int n0 = 0; n0 < 8; n0++) breg[n0] = bp[n0*64 + l];
    }
    {   // initial pht partials from regs (uses corr(0) = cwb[0])
        #pragma unroll
        for (int n0 = 0; n0 < 8; n0++){
            float p = 0.f;
            #pragma unroll
            for (int j = 0; j < 4; j++){
                int row = wv*16 + kb*4 + j;
                p += cwb[0][row]*hreg[n0][j];
            }
            p += __shfl_xor(p, 16);
            p += __shfl_xor(p, 32);
            if (l < 16) phtp[wv][n0*16 + l] = p;
        }
    }
    __syncthreads();
    if (tid < DH_){
        float s = 0.f;
        #pragma unroll
        for (int g = 0; g < 16; g++) s += phtp[g][tid];
        htf[tid] = f2h(s);
    }
    __syncthreads();

    for (int t = 0; t < L_; t++){
        int cb = t & 1, nb = (t+1) & 1;

        // ---- P1: W0-7 G-dot full-K (f16 dot2); W8-15 stage t+1 ----
        if (tid < 512){
            int gx = tid >> 7, gh = tid & 127;
            const uint4* gp = ((const uint4*)gwch) + tid;
            const uint4* htv = (const uint4*)htf;
            float a0 = 0.f, a1 = 0.f;
            #pragma unroll 8
            for (int i8 = 0; i8 < 16; i8++){
                uint4 w = gp[i8*512];
                uint4 h = htv[i8];
                a0 = dot2_(w.x, h.x, a0);
                a1 = dot2_(w.y, h.y, a1);
                a0 = dot2_(w.z, h.z, a0);
                a1 = dot2_(w.w, h.w, a1);
            }
            float acc = a0 + a1;
            if (gx == 3){
                pp[gh] = fsig_(acc + stg[cb][3][gh]);
            } else {
                float v = fsig_((acc + stg[cb][gx][gh])*gtl[cb][gx]);
                ((unsigned short*)sgf)[gx*160 + (gh>>6)*80 + (gh&63)] = f2h(v);
            }
        } else {
            int tc = (t+1 < L_) ? (t+1) : t;
            int btn = b*L_ + tc;
            for (int s = tid-512; s < 899; s += 512){
                if (s < 128)      stg[nb][0][s]     = actT [(size_t)btn*DH_ + s];
                else if (s < 256) stg[nb][1][s-128] = actA [(size_t)btn*DH_ + (s-128)];
                else if (s < 384) stg[nb][2][s-256] = actH [(size_t)btn*DH_ + (s-256)];
                else if (s < 512) stg[nb][3][s-384] = predt[(size_t)btn*DH_ + (s-384)];
                else if (s < 640) stg[nb][4][s-512] = fbase[(size_t)btn*DH_ + (s-512)];
                else if (s < 896){ int qn = q_seq[btn]; cwb[nb][s-640] = q_matrix[(size_t)qn*C_ + (s-640)]; }
                else if (s == 896) gtl[nb][0] = gateT[btn];
                else if (s == 897) gtl[nb][1] = gateA[btn];
                else if (s == 898) gtl[nb][2] = gateH[btn];
            }
        }
        __syncthreads();

        // ---- P2: ALL waves L-dot split-K (f16 dot2) -> lgl; pred-out ----
        {
            const uint4* tp = ((const uint4*)twch) + tid;
            const uint4* ap = ((const uint4*)awch) + tid;
            const uint4* hp = ((const uint4*)hwch) + tid;
            const uint4* sv = (const uint4*)sgf;
            int sb = kh*10;
            float ft = lb0, fa = lb1, fh = lb2;
            #pragma unroll 4
            for (int ii = 0; ii < 8; ii++){
                uint4 ut = tp[ii*1024], ua = ap[ii*1024], uh2 = hp[ii*1024];
                uint4 sx = sv[0*20 + sb + ii];
                uint4 sy = sv[1*20 + sb + ii];
                uint4 sz = sv[2*20 + sb + ii];
                ft = dot2_(ut.x, sx.x, ft); ft = dot2_(ut.y, sx.y, ft);
                ft = dot2_(ut.z, sx.z, ft); ft = dot2_(ut.w, sx.w, ft);
                fa = dot2_(ua.x, sy.x, fa); fa = dot2_(ua.y, sy.y, fa);
                fa = dot2_(ua.z, sy.z, fa); fa = dot2_(ua.w, sy.w, fa);
                fh = dot2_(uh2.x, sz.x, fh); fh = dot2_(uh2.y, sz.y, fh);
                fh = dot2_(uh2.z, sz.z, fh); fh = dot2_(uh2.w, sz.w, fh);
            }
            // combine K-halves (partner = tid^1, same wave)
            ft += __shfl_xor(ft, 1);
            fa += __shfl_xor(fa, 1);
            fh += __shfl_xor(fh, 1);
            float v = wfr*ft*fa*fh;
            v += __shfl_xor(v, 2);
            v += __shfl_xor(v, 4);
            if ((tid & 7) == 0) lgl[hh] = fmaxf(v + cbr, 0.f);
            if (tid < 64){
                float pv = pp[tid] + pp[tid+64];
                pv += __shfl_xor(pv,1); pv += __shfl_xor(pv,2); pv += __shfl_xor(pv,4);
                pv += __shfl_xor(pv,8); pv += __shfl_xor(pv,16); pv += __shfl_xor(pv,32);
                if (tid == 0) out[(size_t)b*L_ + t] = pv*(1.f/DH_);
            }
        }
        __syncthreads();

        // ---- P3: MFMA forget GEMM (kk=0 from regs) + epilogue ----
        {
            const short8_* bp = (const short8_*)bflds;
            short8_ af[4];
            #pragma unroll
            for (int kk = 0; kk < 4; kk++){
                int ar = wv*16 + l15;
                int c0 = (kk*32 + kb*8) ^ ((ar & 7) << 3);
                af[kk] = *(const short8_*)&hl[ar*DH_ + c0];
            }
            float pacc[8] = {0,0,0,0,0,0,0,0};
            #pragma unroll
            for (int n0 = 0; n0 < 8; n0++){
                f32x4_ acc = {0.f,0.f,0.f,0.f};
                acc = __builtin_amdgcn_mfma_f32_16x16x32_bf16(af[0], breg[n0], acc, 0, 0, 0);
                acc = __builtin_amdgcn_mfma_f32_16x16x32_bf16(af[1], bp[(1*8+n0)*64 + l], acc, 0, 0, 0);
                acc = __builtin_amdgcn_mfma_f32_16x16x32_bf16(af[2], bp[(2*8+n0)*64 + l], acc, 0, 0, 0);
                acc = __builtin_amdgcn_mfma_f32_16x16x32_bf16(af[3], bp[(3*8+n0)*64 + l], acc, 0, 0, 0);
                int hc = n0*16 + l15;
                float lgh = lgl[hc], fbh = stg[cb][4][hc];
                #pragma unroll
                for (int j = 0; j < 4; j++){
                    int row = wv*16 + kb*4 + j;
                    float f = fsig_(acc[j] + fbh);
                    float hv = hreg[n0][j]*f + cwb[cb][row]*lgh;
                    hreg[n0][j] = hv;
                    hl[HB(row, hc)] = f2bf_hw(hv);
                    pacc[n0] += cwb[nb][row]*hv;
                }
            }
            #pragma unroll
            for (int n0 = 0; n0 < 8; n0++){
                float p = pacc[n0];
                p += __shfl_xor(p, 16);
                p += __shfl_xor(p, 32);
                if (l < 16) phtp[wv][n0*16 + l] = p;
            }
        }
        __syncthreads();

        // ---- P4: reduce next h_tilde, pack f16 ----
        if (tid < DH_){
            float s = 0.f;
            #pragma unroll
            for (int g = 0; g < 16; g++) s += phtp[g][tid];
            htf[tid] = f2h(s);
        }
        __syncthreads();
    }
}

extern "C" void kernel_launch(void* const* d_in, const int* in_sizes, int n_in,
                              void* d_out, int out_size, void* d_ws, size_t ws_size,
                              hipStream_t stream){
    const int*   q_seq    = (const int*)  d_in[0];
    const int*   c_seq    = (const int*)  d_in[1];
    const float* tfs      = (const float*)d_in[2];
    const float* afs      = (const float*)d_in[3];
    const float* hfs      = (const float*)d_in[4];
    const float* q_matrix = (const float*)d_in[5];
    const float* embQ     = (const float*)d_in[6];
    const float* embC     = (const float*)d_in[7];
    const float* inW      = (const float*)d_in[8];
    const float* inB      = (const float*)d_in[9];
    const float* init_h   = (const float*)d_in[10];
    const float* tgW      = (const float*)d_in[11];
    const float* tgb      = (const float*)d_in[12];
    const float* agW      = (const float*)d_in[13];
    const float* agb      = (const float*)d_in[14];
    const float* hgW      = (const float*)d_in[15];
    const float* hgb      = (const float*)d_in[16];
    const float* tw       = (const float*)d_in[17];
    const float* aw       = (const float*)d_in[18];
    const float* hw       = (const float*)d_in[19];
    const float* Wf       = (const float*)d_in[20];
    const float* cellb    = (const float*)d_in[21];
    const float* g3W      = (const float*)d_in[22];
    const float* g3b      = (const float*)d_in[23];
    const float* outW     = (const float*)d_in[24];
    const float* outb     = (const float*)d_in[25];
    float* out = (float*)d_out;

    float* ws    = (float*)d_ws;
    float* acts  = ws;
    float* actT  = acts  + (size_t)B_*L_*DH_;
    float* actA  = actT  + (size_t)B_*L_*DH_;
    float* actH  = actA  + (size_t)B_*L_*DH_;
    float* fbase = actH  + (size_t)B_*L_*DH_;
    float* predt = fbase + (size_t)B_*L_*DH_;
    float* gateT = predt + (size_t)B_*L_*DH_;
    float* gateA = gateT + (size_t)B_*L_;
    float* gateH = gateA + (size_t)B_*L_;
    float* ssum  = gateH + (size_t)B_*L_;                 // 384 floats
    float* lbias = ssum  + 3*DH_ + 64;                    // 16B aligned
    unsigned short* gwch = (unsigned short*)(lbias + 3*4*DH_);  // 65536 shorts
    unsigned short* twch = gwch + 65536;
    unsigned short* awch = twch + 65536;
    unsigned short* hwch = awch + 65536;

    k_ssum <<<1, 128, 0, stream>>>(g3W, ssum);
    k_acts4<<<B_*L_/4, 128, 0, stream>>>(q_seq, c_seq, embQ, embC, inW, inB, acts);
    k_base4<<<B_*L_/4, 128, 0, stream>>>(q_seq, tfs, afs, hfs, acts, embQ,
                                         tgW, tgb, agW, agb, hgW, hgb, g3W, g3b,
                                         outW, outb, ssum,
                                         actT, actA, actH, fbase, predt,
                                         gateT, gateA, gateH);
    k_wG<<<256, 256, 0, stream>>>(tgW, agW, hgW, outW, gwch);
    k_wL<<<(3*65536 + 3*4*DH_ + 255)/256, 256, 0, stream>>>(tw, aw, hw, twch, awch, hwch, lbias);
    k_one<<<B_, 1024, 0, stream>>>(q_seq, q_matrix, init_h, g3W,
                                   gwch, twch, awch, hwch, lbias, Wf, cellb,
                                   actT, actA, actH, fbase, predt,
                                   gateT, gateA, gateH, out);
}

// Round 13
// 1455.795 us; speedup vs baseline: 1.3000x; 1.3000x over previous
//
#include <hip/hip_runtime.h>
#include <hip/hip_bf16.h>
#include <hip/hip_fp16.h>

#define B_ 64
#define L_ 128
#define C_ 256
#define DH_ 128
#define DF_ 50
#define R_ 4

typedef __attribute__((ext_vector_type(8))) short short8_;
typedef __attribute__((ext_vector_type(4))) float f32x4_;
typedef _Float16 half2_ __attribute__((ext_vector_type(2)));

__device__ __forceinline__ float sigmoidf_(float x){ return 1.0f/(1.0f+expf(-x)); }
// fast sigmoid: v_rcp approx (~1e-6 rel) instead of precise division; tol is 2e-3.
// R12 counters confirmed: VALUBusy 11.75 -> 6.95 from this (register-neutral).
__device__ __forceinline__ float fsig_(float x){
#if __has_builtin(__builtin_amdgcn_rcpf)
    return __builtin_amdgcn_rcpf(1.0f + __expf(-x));
#else
    return 1.0f/(1.0f+__expf(-x));
#endif
}

__device__ __forceinline__ unsigned short f2bf(float f){
    unsigned u = __builtin_bit_cast(unsigned, f);
    unsigned r = (u + 0x7FFFu + ((u >> 16) & 1u)) >> 16;
    return (unsigned short)r;
}
__device__ __forceinline__ unsigned short f2bf_hw(float f){
    return __builtin_bit_cast(unsigned short, __float2bfloat16(f));
}
__device__ __host__ __forceinline__ unsigned short f2h(float f){
    return __builtin_bit_cast(unsigned short, (_Float16)f);
}
// packed f16 dot: acc += a.lo*b.lo + a.hi*b.hi  (v_dot2_f32_f16 if available)
__device__ __forceinline__ float dot2_(unsigned a, unsigned b, float c){
#if __has_builtin(__builtin_amdgcn_fdot2)
    return __builtin_amdgcn_fdot2(__builtin_bit_cast(half2_, a),
                                  __builtin_bit_cast(half2_, b), c, false);
#else
    half2_ ah = __builtin_bit_cast(half2_, a), bh = __builtin_bit_cast(half2_, b);
    return c + (float)ah.x*(float)bh.x + (float)ah.y*(float)bh.y;
#endif
}

// bf16 h-state swizzle (8-col groups XORed by row&7)
#define HB(r,c) ((r)*128 + ((c) ^ (((r)&7)<<3)))

// ---------------- Precompute: column sums of gate3_W factor rows ----------------
__global__ void k_ssum(const float* __restrict__ g3W, float* __restrict__ ssum){
    int h = threadIdx.x;
    for (int s = 0; s < 3; s++){
        float a = 0.f;
        for (int j = 0; j < DF_; j++) a += g3W[(2*DH_ + s*DF_ + j)*DH_ + h];
        ssum[s*DH_ + h] = a;
    }
}

// ------- Precompute: acts -------------------------------------------------------
__global__ void k_acts4(const int* __restrict__ q_seq, const int* __restrict__ c_seq,
                        const float* __restrict__ embQ, const float* __restrict__ embC,
                        const float* __restrict__ inW, const float* __restrict__ inB,
                        float* __restrict__ acts){
    int bt0 = blockIdx.x*4; int h = threadIdx.x;
    __shared__ float qe[4][DH_], ce[4][DH_];
    #pragma unroll
    for (int s = 0; s < 4; s++){
        qe[s][h] = embQ[(size_t)q_seq[bt0+s]*DH_ + h];
        ce[s][h] = embC[(size_t)c_seq[bt0+s]*DH_ + h];
    }
    __syncthreads();
    float a0 = inB[h], a1 = a0, a2 = a0, a3 = a0;
    for (int i = 0; i < DH_; i++){
        float w = inW[i*DH_ + h];
        a0 += qe[0][i]*w; a1 += qe[1][i]*w; a2 += qe[2][i]*w; a3 += qe[3][i]*w;
    }
    for (int i = 0; i < DH_; i++){
        float w = inW[(DH_+i)*DH_ + h];
        a0 += ce[0][i]*w; a1 += ce[1][i]*w; a2 += ce[2][i]*w; a3 += ce[3][i]*w;
    }
    acts[(size_t)(bt0+0)*DH_+h] = fmaxf(a0,0.f);
    acts[(size_t)(bt0+1)*DH_+h] = fmaxf(a1,0.f);
    acts[(size_t)(bt0+2)*DH_+h] = fmaxf(a2,0.f);
    acts[(size_t)(bt0+3)*DH_+h] = fmaxf(a3,0.f);
}

// ------- Precompute: per-(b,t) bias bases + gates -------------------------------
__global__ void k_base4(const int* __restrict__ q_seq,
                        const float* __restrict__ tfs, const float* __restrict__ afs,
                        const float* __restrict__ hfs,
                        const float* __restrict__ acts, const float* __restrict__ embQ,
                        const float* __restrict__ tgW, const float* __restrict__ tgb,
                        const float* __restrict__ agW, const float* __restrict__ agb,
                        const float* __restrict__ hgW, const float* __restrict__ hgb,
                        const float* __restrict__ g3W, const float* __restrict__ g3b,
                        const float* __restrict__ outW, const float* __restrict__ outb,
                        const float* __restrict__ ssum,
                        float* __restrict__ actT, float* __restrict__ actA,
                        float* __restrict__ actH,
                        float* __restrict__ fbase, float* __restrict__ predt,
                        float* __restrict__ gateT, float* __restrict__ gateA,
                        float* __restrict__ gateH){
    int bt0 = blockIdx.x*4; int h = threadIdx.x;
    __shared__ float al[4][DH_], qe[4][DH_];
    #pragma unroll
    for (int s = 0; s < 4; s++){
        al[s][h] = acts[(size_t)(bt0+s)*DH_ + h];
        qe[s][h] = embQ[(size_t)q_seq[bt0+s]*DH_ + h];
    }
    __syncthreads();
    float aT[4]={0,0,0,0}, aA[4]={0,0,0,0}, aH[4]={0,0,0,0}, aF[4]={0,0,0,0}, aP[4]={0,0,0,0};
    for (int i = 0; i < DH_; i++){
        float wt = tgW[(DH_+i)*DH_+h];
        float wa = agW[(DH_+i)*DH_+h];
        float wh = hgW[(DH_+i)*DH_+h];
        float wf = g3W[(DH_+i)*DH_+h];
        float wo = outW[(DH_+i)*DH_+h];
        #pragma unroll
        for (int s = 0; s < 4; s++){
            float av = al[s][i], qv = qe[s][i];
            aT[s] += av*wt; aA[s] += av*wa; aH[s] += av*wh;
            aF[s] += av*wf; aP[s] += qv*wo;
        }
    }
    #pragma unroll
    for (int s = 0; s < 4; s++){
        int bt = bt0 + s;
        actT[(size_t)bt*DH_+h]  = aT[s] + tgb[h];
        actA[(size_t)bt*DH_+h]  = aA[s] + agb[h];
        actH[(size_t)bt*DH_+h]  = aH[s] + hgb[h];
        fbase[(size_t)bt*DH_+h] = aF[s] + g3b[h]
            + tfs[bt]*ssum[h] + afs[bt]*ssum[DH_+h] + hfs[bt]*ssum[2*DH_+h];
        predt[(size_t)bt*DH_+h] = aP[s] + outb[h];
    }
    if (h == 0){
        #pragma unroll
        for (int s = 0; s < 4; s++){
            int bt = bt0+s;
            gateT[bt] = 0.7f + 0.3f*sigmoidf_(10.f*(tfs[bt]-0.3f));
            gateA[bt] = 0.7f + 0.3f*sigmoidf_(10.f*(afs[bt]-0.3f));
            gateH[bt] = 0.7f + 0.3f*sigmoidf_(10.f*(hfs[bt]-0.3f));
        }
    }
}

// ------- Precompute: G weights, COALESCED layout, f16 --------------------------
// gwch[(i8*512 + gx*128 + gh)*8 + j] = f16( W_gx[(i8*8+j)*128 + gh] )
__global__ void k_wG(const float* __restrict__ tgW, const float* __restrict__ agW,
                     const float* __restrict__ hgW, const float* __restrict__ outW,
                     unsigned short* __restrict__ gwch){
    int flat = blockIdx.x*256 + threadIdx.x;     // < 65536
    int j = flat & 7, t512 = (flat >> 3) & 511, i8 = flat >> 12;
    int gx = t512 >> 7, gh = t512 & 127, i = i8*8 + j;
    const float* W = (gx==0)?tgW:((gx==1)?agW:((gx==2)?hgW:outW));
    gwch[flat] = f2h(W[i*DH_ + gh]);
}
// ------- Precompute: L weights, COALESCED blocked split-K, f16 -----------------
// thread tidv: hh=tidv>>3, rr=(tidv>>1)&3, kh=tidv&1
// dst[(ii*1024 + tidv)*8 + j] = f16( w[(rr*129 + kh*64 + ii*8 + j)*128 + hh] )
__global__ void k_wL(const float* __restrict__ tw, const float* __restrict__ aw,
                     const float* __restrict__ hw,
                     unsigned short* __restrict__ twch, unsigned short* __restrict__ awch,
                     unsigned short* __restrict__ hwch, float* __restrict__ lbias){
    int flat = blockIdx.x*256 + threadIdx.x;
    if (flat < 3*65536){
        int m = flat >> 16, fi = flat & 65535;
        int j = fi & 7, tidv = (fi >> 3) & 1023, ii = fi >> 13;
        int hh = tidv >> 3, rr = (tidv >> 1) & 3, kh = tidv & 1;
        int i = kh*64 + ii*8 + j;
        const float* w = (m==0)?tw:((m==1)?aw:hw);
        unsigned short* dst = (m==0)?twch:((m==1)?awch:hwch);
        dst[fi] = f2h(w[((size_t)(rr*129 + i))*DH_ + hh]);
    } else if (flat < 3*65536 + 3*4*128){
        int f2 = flat - 3*65536;
        int m = f2 >> 9, r = (f2 >> 7) & 3, h = f2 & 127;
        const float* w = (m==0)?tw:((m==1)?aw:hw);
        lbias[f2] = w[((size_t)(r*129 + 128))*DH_ + h];
    }
}

// ---------------- Recurrence: one block per b, 1024 threads, 16 waves ----------
// EXACT R9 skeleton (best: 1705us, no spill) + register-neutral deltas only:
// rcp-sigmoid (R12-proven -5pp VALUBusy) and pred-out in P2 (phase balance).
// NO per-thread arrays beyond R9's: 64-VGPR budget is a hard wall (R4/R6/R10/R12
// all spilled any addition; waves_per_eu did not raise it).
//  P1: W0-7 G-dot full-K (f16 dot2); W8-15 stage t+1
//  P2: ALL waves L-dot split-K (f16 dot2) -> lgl; pred-out from pp
//  P3: MFMA forget + epilogue
//  P4: reduce htl(t+1), store packed f16
__global__ __launch_bounds__(1024, 1)
void k_one(const int* __restrict__ q_seq, const float* __restrict__ q_matrix,
           const float* __restrict__ init_h, const float* __restrict__ g3W,
           const unsigned short* __restrict__ gwch,
           const unsigned short* __restrict__ twch, const unsigned short* __restrict__ awch,
           const unsigned short* __restrict__ hwch,
           const float* __restrict__ lbias, const float* __restrict__ Wf,
           const float* __restrict__ cellb,
           const float* __restrict__ actT, const float* __restrict__ actA,
           const float* __restrict__ actH,
           const float* __restrict__ fbase, const float* __restrict__ predt,
           const float* __restrict__ gateT, const float* __restrict__ gateA,
           const float* __restrict__ gateH,
           float* __restrict__ out){
    int b = blockIdx.x;
    int tid = threadIdx.x;
    int l = tid & 63, wv = tid >> 6, kb = l >> 4, l15 = l & 15;

    __shared__ unsigned short hl[C_*DH_];        // 64 KB bf16 h state (wave-private rows)
    __shared__ unsigned short bflds[2048*8];     // 32 KB g3W B-fragments
    __shared__ float phtp[16][DH_];              // 8 KB
    __shared__ __align__(16) unsigned short htf[DH_];   // h_tilde packed f16
    __shared__ __align__(16) unsigned sgf[3*80]; // gates f16: x*80 + kh*40 + e(32)
    __shared__ float pp[DH_];
    __shared__ float lgl[DH_];
    __shared__ float stg[2][5][DH_];             // actT,actA,actH,predt,fbase
    __shared__ float gtl[2][4];
    __shared__ float cwb[2][C_];                 // corr_w double-buffer

    // L-dot ids (blocked split-K)
    int kh = tid & 1;
    int rr3 = (tid >> 1) & 3, hh = tid >> 3;
    float kmask = kh ? 0.f : 1.f;
    float lb0 = kmask*lbias[(0*4+rr3)*DH_ + hh];
    float lb1 = kmask*lbias[(1*4+rr3)*DH_ + hh];
    float lb2 = kmask*lbias[(2*4+rr3)*DH_ + hh];
    float wfr = Wf[rr3];
    float cbr = cellb[hh];

    // build B-fragments in LDS (2 per thread)
    #pragma unroll
    for (int ff = 0; ff < 2; ff++){
        int f = tid*2 + ff;
        int fl = f & 63, fn0 = (f >> 6) & 7, fkk = f >> 9;
        #pragma unroll
        for (int j = 0; j < 8; j++){
            int k = fkk*32 + (fl>>4)*8 + j;
            int n = fn0*16 + (fl&15);
            bflds[f*8 + j] = f2bf(g3W[k*DH_ + n]);
        }
    }

    // h-regs init: wave owns 16 rows (wv*16..+15), all cols
    float hreg[8][4];
    #pragma unroll
    for (int n0 = 0; n0 < 8; n0++)
    #pragma unroll
    for (int j = 0; j < 4; j++){
        int row = wv*16 + kb*4 + j;
        int hc = n0*16 + l15;
        float v = init_h[row*DH_ + hc];
        hreg[n0][j] = v;
        hl[HB(row, hc)] = f2bf(v);
    }
    // pre-loop staging of buffer 0 (t=0 data)
    {
        int bt0 = b*L_;
        int s = tid;
        if (s < 128)      stg[0][0][s]     = actT [(size_t)bt0*DH_ + s];
        else if (s < 256) stg[0][1][s-128] = actA [(size_t)bt0*DH_ + (s-128)];
        else if (s < 384) stg[0][2][s-256] = actH [(size_t)bt0*DH_ + (s-256)];
        else if (s < 512) stg[0][3][s-384] = predt[(size_t)bt0*DH_ + (s-384)];
        else if (s < 640) stg[0][4][s-512] = fbase[(size_t)bt0*DH_ + (s-512)];
        else if (s < 896){ int q0 = q_seq[bt0]; cwb[0][s-640] = q_matrix[(size_t)q0*C_ + (s-640)]; }
        else if (s == 896) gtl[0][0] = gateT[bt0];
        else if (s == 897) gtl[0][1] = gateA[bt0];
        else if (s == 898) gtl[0][2] = gateH[bt0];
    }
    __syncthreads();
    {   // initial pht partials from regs (uses corr(0) = cwb[0])
        #pragma unroll
        for (int n0 = 0; n0 < 8; n0++){
            float p = 0.f;
            #pragma unroll
            for (int j = 0; j < 4; j++){
                int row = wv*16 + kb*4 + j;
                p += cwb[0][row]*hreg[n0][j];
            }
            p += __shfl_xor(p, 16);
            p += __shfl_xor(p, 32);
            if (l < 16) phtp[wv][n0*16 + l] = p;
        }
    }
    __syncthreads();
    if (tid < DH_){
        float s = 0.f;
        #pragma unroll
        for (int g = 0; g < 16; g++) s += phtp[g][tid];
        htf[tid] = f2h(s);
    }
    __syncthreads();

    for (int t = 0; t < L_; t++){
        int cb = t & 1, nb = (t+1) & 1;

        // ---- P1: W0-7 G-dot full-K (f16 dot2); W8-15 stage t+1 ----
        if (tid < 512){
            int gx = tid >> 7, gh = tid & 127;
            const uint4* gp = ((const uint4*)gwch) + tid;
            const uint4* htv = (const uint4*)htf;
            float a0 = 0.f, a1 = 0.f;
            #pragma unroll 8
            for (int i8 = 0; i8 < 16; i8++){
                uint4 w = gp[i8*512];
                uint4 h = htv[i8];
                a0 = dot2_(w.x, h.x, a0);
                a1 = dot2_(w.y, h.y, a1);
                a0 = dot2_(w.z, h.z, a0);
                a1 = dot2_(w.w, h.w, a1);
            }
            float acc = a0 + a1;
            if (gx == 3){
                pp[gh] = fsig_(acc + stg[cb][3][gh]);
            } else {
                float v = fsig_((acc + stg[cb][gx][gh])*gtl[cb][gx]);
                ((unsigned short*)sgf)[gx*160 + (gh>>6)*80 + (gh&63)] = f2h(v);
            }
        } else {
            int tc = (t+1 < L_) ? (t+1) : t;
            int btn = b*L_ + tc;
            for (int s = tid-512; s < 899; s += 512){
                if (s < 128)      stg[nb][0][s]     = actT [(size_t)btn*DH_ + s];
                else if (s < 256) stg[nb][1][s-128] = actA [(size_t)btn*DH_ + (s-128)];
                else if (s < 384) stg[nb][2][s-256] = actH [(size_t)btn*DH_ + (s-256)];
                else if (s < 512) stg[nb][3][s-384] = predt[(size_t)btn*DH_ + (s-384)];
                else if (s < 640) stg[nb][4][s-512] = fbase[(size_t)btn*DH_ + (s-512)];
                else if (s < 896){ int qn = q_seq[btn]; cwb[nb][s-640] = q_matrix[(size_t)qn*C_ + (s-640)]; }
                else if (s == 896) gtl[nb][0] = gateT[btn];
                else if (s == 897) gtl[nb][1] = gateA[btn];
                else if (s == 898) gtl[nb][2] = gateH[btn];
            }
        }
        __syncthreads();

        // ---- P2: ALL waves L-dot split-K (f16 dot2) -> lgl; pred-out ----
        {
            const uint4* tp = ((const uint4*)twch) + tid;
            const uint4* ap = ((const uint4*)awch) + tid;
            const uint4* hp = ((const uint4*)hwch) + tid;
            const uint4* sv = (const uint4*)sgf;
            int sb = kh*10;
            float ft = lb0, fa = lb1, fh = lb2;
            #pragma unroll 4
            for (int ii = 0; ii < 8; ii++){
                uint4 ut = tp[ii*1024], ua = ap[ii*1024], uh2 = hp[ii*1024];
                uint4 sx = sv[0*20 + sb + ii];
                uint4 sy = sv[1*20 + sb + ii];
                uint4 sz = sv[2*20 + sb + ii];
                ft = dot2_(ut.x, sx.x, ft); ft = dot2_(ut.y, sx.y, ft);
                ft = dot2_(ut.z, sx.z, ft); ft = dot2_(ut.w, sx.w, ft);
                fa = dot2_(ua.x, sy.x, fa); fa = dot2_(ua.y, sy.y, fa);
                fa = dot2_(ua.z, sy.z, fa); fa = dot2_(ua.w, sy.w, fa);
                fh = dot2_(uh2.x, sz.x, fh); fh = dot2_(uh2.y, sz.y, fh);
                fh = dot2_(uh2.z, sz.z, fh); fh = dot2_(uh2.w, sz.w, fh);
            }
            // combine K-halves (partner = tid^1, same wave)
            ft += __shfl_xor(ft, 1);
            fa += __shfl_xor(fa, 1);
            fh += __shfl_xor(fh, 1);
            float v = wfr*ft*fa*fh;
            v += __shfl_xor(v, 2);
            v += __shfl_xor(v, 4);
            if ((tid & 7) == 0) lgl[hh] = fmaxf(v + cbr, 0.f);
            if (tid < 64){
                float pv = pp[tid] + pp[tid+64];
                pv += __shfl_xor(pv,1); pv += __shfl_xor(pv,2); pv += __shfl_xor(pv,4);
                pv += __shfl_xor(pv,8); pv += __shfl_xor(pv,16); pv += __shfl_xor(pv,32);
                if (tid == 0) out[(size_t)b*L_ + t] = pv*(1.f/DH_);
            }
        }
        __syncthreads();

        // ---- P3: MFMA forget GEMM + epilogue ----
        {
            const short8_* bp = (const short8_*)bflds;
            short8_ af[4];
            #pragma unroll
            for (int kk = 0; kk < 4; kk++){
                int ar = wv*16 + l15;
                int c0 = (kk*32 + kb*8) ^ ((ar & 7) << 3);
                af[kk] = *(const short8_*)&hl[ar*DH_ + c0];
            }
            float pacc[8] = {0,0,0,0,0,0,0,0};
            #pragma unroll
            for (int n0 = 0; n0 < 8; n0++){
                f32x4_ acc = {0.f,0.f,0.f,0.f};
                acc = __builtin_amdgcn_mfma_f32_16x16x32_bf16(af[0], bp[(0*8+n0)*64 + l], acc, 0, 0, 0);
                acc = __builtin_amdgcn_mfma_f32_16x16x32_bf16(af[1], bp[(1*8+n0)*64 + l], acc, 0, 0, 0);
                acc = __builtin_amdgcn_mfma_f32_16x16x32_bf16(af[2], bp[(2*8+n0)*64 + l], acc, 0, 0, 0);
                acc = __builtin_amdgcn_mfma_f32_16x16x32_bf16(af[3], bp[(3*8+n0)*64 + l], acc, 0, 0, 0);
                int hc = n0*16 + l15;
                float lgh = lgl[hc], fbh = stg[cb][4][hc];
                #pragma unroll
                for (int j = 0; j < 4; j++){
                    int row = wv*16 + kb*4 + j;
                    float f = fsig_(acc[j] + fbh);
                    float hv = hreg[n0][j]*f + cwb[cb][row]*lgh;
                    hreg[n0][j] = hv;
                    hl[HB(row, hc)] = f2bf_hw(hv);
                    pacc[n0] += cwb[nb][row]*hv;
                }
            }
            #pragma unroll
            for (int n0 = 0; n0 < 8; n0++){
                float p = pacc[n0];
                p += __shfl_xor(p, 16);
                p += __shfl_xor(p, 32);
                if (l < 16) phtp[wv][n0*16 + l] = p;
            }
        }
        __syncthreads();

        // ---- P4: reduce next h_tilde, pack f16 ----
        if (tid < DH_){
            float s = 0.f;
            #pragma unroll
            for (int g = 0; g < 16; g++) s += phtp[g][tid];
            htf[tid] = f2h(s);
        }
        __syncthreads();
    }
}

extern "C" void kernel_launch(void* const* d_in, const int* in_sizes, int n_in,
                              void* d_out, int out_size, void* d_ws, size_t ws_size,
                              hipStream_t stream){
    const int*   q_seq    = (const int*)  d_in[0];
    const int*   c_seq    = (const int*)  d_in[1];
    const float* tfs      = (const float*)d_in[2];
    const float* afs      = (const float*)d_in[3];
    const float* hfs      = (const float*)d_in[4];
    const float* q_matrix = (const float*)d_in[5];
    const float* embQ     = (const float*)d_in[6];
    const float* embC     = (const float*)d_in[7];
    const float* inW      = (const float*)d_in[8];
    const float* inB      = (const float*)d_in[9];
    const float* init_h   = (const float*)d_in[10];
    const float* tgW      = (const float*)d_in[11];
    const float* tgb      = (const float*)d_in[12];
    const float* agW      = (const float*)d_in[13];
    const float* agb      = (const float*)d_in[14];
    const float* hgW      = (const float*)d_in[15];
    const float* hgb      = (const float*)d_in[16];
    const float* tw       = (const float*)d_in[17];
    const float* aw       = (const float*)d_in[18];
    const float* hw       = (const float*)d_in[19];
    const float* Wf       = (const float*)d_in[20];
    const float* cellb    = (const float*)d_in[21];
    const float* g3W      = (const float*)d_in[22];
    const float* g3b      = (const float*)d_in[23];
    const float* outW     = (const float*)d_in[24];
    const float* outb     = (const float*)d_in[25];
    float* out = (float*)d_out;

    float* ws    = (float*)d_ws;
    float* acts  = ws;
    float* actT  = acts  + (size_t)B_*L_*DH_;
    float* actA  = actT  + (size_t)B_*L_*DH_;
    float* actH  = actA  + (size_t)B_*L_*DH_;
    float* fbase = actH  + (size_t)B_*L_*DH_;
    float* predt = fbase + (size_t)B_*L_*DH_;
    float* gateT = predt + (size_t)B_*L_*DH_;
    float* gateA = gateT + (size_t)B_*L_;
    float* gateH = gateA + (size_t)B_*L_;
    float* ssum  = gateH + (size_t)B_*L_;                 // 384 floats
    float* lbias = ssum  + 3*DH_ + 64;                    // 16B aligned
    unsigned short* gwch = (unsigned short*)(lbias + 3*4*DH_);  // 65536 shorts
    unsigned short* twch = gwch + 65536;
    unsigned short* awch = twch + 65536;
    unsigned short* hwch = awch + 65536;

    k_ssum <<<1, 128, 0, stream>>>(g3W, ssum);
    k_acts4<<<B_*L_/4, 128, 0, stream>>>(q_seq, c_seq, embQ, embC, inW, inB, acts);
    k_base4<<<B_*L_/4, 128, 0, stream>>>(q_seq, tfs, afs, hfs, acts, embQ,
                                         tgW, tgb, agW, agb, hgW, hgb, g3W, g3b,
                                         outW, outb, ssum,
                                         actT, actA, actH, fbase, predt,
                                         gateT, gateA, gateH);
    k_wG<<<256, 256, 0, stream>>>(tgW, agW, hgW, outW, gwch);
    k_wL<<<(3*65536 + 3*4*DH_ + 255)/256, 256, 0, stream>>>(tw, aw, hw, twch, awch, hwch, lbias);
    k_one<<<B_, 1024, 0, stream>>>(q_seq, q_matrix, init_h, g3W,
                                   gwch, twch, awch, hwch, lbias, Wf, cellb,
                                   actT, actA, actH, fbase, predt,
                                   gateT, gateA, gateH, out);
}